// Round 4
// baseline (515.544 us; speedup 1.0000x reference)
//
#include <hip/hip_runtime.h>
#include <math.h>

#define NBATCH 4
#define PRE 1024
#define CAND 4096
#define NHIST 65536
#define MAXSLOT 384

__device__ __forceinline__ unsigned long long allow_mask(int i, int l) {
    // bits j in word l with j > i
    int base = l << 6;
    if (i < base) return ~0ull;
    int sh = i - base + 1;
    if (sh >= 64) return 0ull;
    return (~0ull) << sh;
}

// K_INIT: blocks 0..255 zero hist (1MB); block 256 builds split weights.
__global__ __launch_bounds__(256) void k_init(
    const float* __restrict__ Wcls, const float* __restrict__ bcls,
    const float* __restrict__ Wreg, const float* __restrict__ breg,
    double* __restrict__ Wd3, float* __restrict__ Wf8,
    double* __restrict__ biasD, float* __restrict__ biasF,
    unsigned int* __restrict__ hist) {
    int blk = blockIdx.x, t = threadIdx.x;
    if (blk < 256) {
        uint4* H = (uint4*)hist;
        H[blk * 256 + t] = make_uint4(0u, 0u, 0u, 0u);
    } else {
        int c = t;   // channel 0..255
        Wd3[0 * 256 + c] = (double)Wcls[c * 2 + 0];
        Wd3[1 * 256 + c] = (double)Wcls[c * 2 + 1];
        Wd3[2 * 256 + c] = (double)Wreg[c * 9 + 8];
#pragma unroll
        for (int r = 0; r < 8; ++r) Wf8[r * 256 + c] = Wreg[c * 9 + r];
        if (c == 0) {
            biasD[0] = (double)bcls[0];
            biasD[1] = (double)bcls[1];
            biasD[2] = (double)breg[8];
#pragma unroll
            for (int r = 0; r < 8; ++r) biasF[r] = breg[r];
        }
    }
}

// K1: 256 pts/block, 8 chunks of 32 ch; register-prefetch next chunk while computing.
// Staging: wave op = 8 points x 8 float4 = 8 full 128B lines. LDS stride 33 (conflict-free reads).
// Weights wave-uniform (scalar loads). f64 acc for 3 score cols, f32 for 8 box cols.
__global__ __launch_bounds__(256, 4) void k1_points(
    const float4* __restrict__ feat4, const int* __restrict__ batch_idx,
    const int* __restrict__ coor, const double* __restrict__ Wd3,
    const float* __restrict__ Wf8, const double* __restrict__ biasD,
    const float* __restrict__ biasF, float* __restrict__ pointData,
    unsigned long long* __restrict__ keys, unsigned int* __restrict__ hist, int N) {
    __shared__ float sfeat[256 * 33];   // 33792 B
    int t = threadIdx.x;
    int p0 = blockIdx.x * 256;
    int sj = t & 7;                      // staging: f4 index within chunk
    int sp = t >> 3;                     // staging: point subgroup

    double a0 = 0.0, a1 = 0.0, a2 = 0.0;
    float f[8] = {0.f, 0.f, 0.f, 0.f, 0.f, 0.f, 0.f, 0.f};
    float4 R[8], R2[8];

    // prefetch chunk 0
#pragma unroll
    for (int r = 0; r < 8; ++r) {
        int gp = p0 + r * 32 + sp;
        R[r] = (gp < N) ? feat4[(size_t)gp * 64 + sj] : make_float4(0.f, 0.f, 0.f, 0.f);
    }

    for (int c = 0; c < 8; ++c) {
        // store prefetched chunk c to LDS (stride 33 floats)
#pragma unroll
        for (int r = 0; r < 8; ++r) {
            float* d = sfeat + (r * 32 + sp) * 33 + sj * 4;
            d[0] = R[r].x; d[1] = R[r].y; d[2] = R[r].z; d[3] = R[r].w;
        }
        __syncthreads();
        if (c < 7) {
#pragma unroll
            for (int r = 0; r < 8; ++r) {
                int gp = p0 + r * 32 + sp;
                R2[r] = (gp < N) ? feat4[(size_t)gp * 64 + (c + 1) * 8 + sj]
                                 : make_float4(0.f, 0.f, 0.f, 0.f);
            }
        }
        const double* wD = Wd3 + c * 32;     // wave-uniform
        const float* wF = Wf8 + c * 32;
#pragma unroll
        for (int k = 0; k < 32; ++k) {
            float v = sfeat[t * 33 + k];     // bank (t+k)%32: conflict-free
            double vd = (double)v;
            a0 = fma(vd, wD[k], a0);
            a1 = fma(vd, wD[256 + k], a1);
            a2 = fma(vd, wD[512 + k], a2);
#pragma unroll
            for (int q = 0; q < 8; ++q) f[q] = fmaf(v, wF[q * 256 + k], f[q]);
        }
        __syncthreads();
#pragma unroll
        for (int r = 0; r < 8; ++r) R[r] = R2[r];
    }

    int p = p0 + t;
    if (p >= N) return;

    double d0 = a0 + biasD[0], d1 = a1 + biasD[1], d2 = a2 + biasD[2];
    double conf = 1.0 / (1.0 + exp(-(d1 - d0)));   // softmax(2)[1]
    double scr = 1.0 / (1.0 + exp(-d2));
    double score = conf * scr;                      // > 0
    float s32 = (float)score;

    float fb[8];
#pragma unroll
    for (int q = 0; q < 8; ++q) fb[q] = f[q] + biasF[q];

    float cx = (float)coor[2 * p] * 0.8f;
    float cy = (float)coor[2 * p + 1] * 0.8f;
    float bx = cx + fb[0], by = cy + fb[1], bz = fb[2];
    float bl = expf(fminf(fmaxf(fb[3], -6.f), 6.f));
    float bw = expf(fminf(fmaxf(fb[4], -6.f), 6.f));
    float bh = expf(fminf(fmaxf(fb[5], -6.f), 6.f));
    float ba = atan2f(fb[6], fb[7]);

    float4* pd = (float4*)(pointData + (size_t)p * 8);
    pd[0] = make_float4(bx, by, bz, bl);
    pd[1] = make_float4(bw, bh, ba, s32);
    keys[p] = (unsigned long long)__double_as_longlong(score);
    int b = batch_idx[p];
    atomicAdd(&hist[b * NHIST + (__float_as_uint(s32) >> 16)], 1u);
}

// K2: per-batch threshold bucket — coalesced chunk sums + parallel suffix scan.
__global__ __launch_bounds__(256) void k2_thresh(const unsigned int* __restrict__ hist,
                                                 unsigned int* __restrict__ Tarr,
                                                 unsigned int* __restrict__ candCount) {
    int b = blockIdx.x, t = threadIdx.x;
    int w = t >> 6, lane = t & 63;
    __shared__ unsigned int bufA[256];
    __shared__ unsigned int bufB[256];
    __shared__ int tcSh;
    __shared__ int mSh;
    if (t == 0) { candCount[b] = 0u; tcSh = -1; mSh = -1; }
    const unsigned int* h = hist + b * NHIST;
    // chunk sums: wave w handles chunks c = i*4 + w; one coalesced 1KB row per chunk
    for (int i = 0; i < 64; ++i) {
        int c = i * 4 + w;
        const uint4* row = (const uint4*)(h + c * 256);
        uint4 v = row[lane];
        unsigned int s = v.x + v.y + v.z + v.w;
#pragma unroll
        for (int off = 1; off < 64; off <<= 1) s += __shfl_xor(s, off, 64);
        if (lane == 0) bufA[c] = s;
    }
    __syncthreads();
    // suffix Kogge-Stone (ping-pong)
    unsigned int* src = bufA; unsigned int* dst = bufB;
#pragma unroll
    for (int d = 1; d < 256; d <<= 1) {
        unsigned int v = src[t] + ((t + d < 256) ? src[t + d] : 0u);
        __syncthreads();
        dst[t] = v;
        __syncthreads();
        unsigned int* tmp = src; src = dst; dst = tmp;
    }
    // src[t] = suffix sum of chunk sums from t..255 (non-increasing in t)
    if (src[t] >= 1024u) atomicMax(&tcSh, t);
    __syncthreads();
    int tc = tcSh;
    if (tc < 0) { if (t == 0) Tarr[b] = 0u; return; }
    unsigned int cum = (tc < 255) ? src[tc + 1] : 0u;
    __syncthreads();
    // pass 2: within chunk tc
    bufA[t] = h[tc * 256 + t];
    __syncthreads();
    src = bufA; dst = bufB;
#pragma unroll
    for (int d = 1; d < 256; d <<= 1) {
        unsigned int v = src[t] + ((t + d < 256) ? src[t + d] : 0u);
        __syncthreads();
        dst[t] = v;
        __syncthreads();
        unsigned int* tmp = src; src = dst; dst = tmp;
    }
    if (cum + src[t] >= 1024u) atomicMax(&mSh, t);
    __syncthreads();
    if (t == 0) Tarr[b] = (unsigned int)(tc * 256 + mSh);
}

// K3: compact candidates (bucket >= threshold bucket)
__global__ void k3_compact(const int* __restrict__ batch_idx, const float* __restrict__ pointData,
                           const unsigned long long* __restrict__ keys,
                           const unsigned int* __restrict__ Tarr, unsigned int* __restrict__ candCount,
                           unsigned int* __restrict__ candIdx, unsigned long long* __restrict__ candKey,
                           int N) {
    int p = blockIdx.x * 256 + threadIdx.x;
    if (p >= N) return;
    int b = batch_idx[p];
    float s32 = pointData[(size_t)p * 8 + 7];
    unsigned int bucket = __float_as_uint(s32) >> 16;
    if (bucket >= Tarr[b]) {
        unsigned int pos = atomicAdd(&candCount[b], 1u);
        if (pos < CAND) {
            candIdx[b * CAND + pos] = (unsigned int)p;
            candKey[b * CAND + pos] = keys[p];
        }
    }
}

// K4: exact rank-selection (no sort): rank_i = #{j: key_j > key_i || (== && idx_j < idx_i)};
// scatter candidate i to row rank_i if rank_i < 1024. Ranks 0..min(cnt,1024)-1 each written once.
__global__ __launch_bounds__(1024) void k4_rank(const unsigned int* __restrict__ candCount,
                                                const unsigned int* __restrict__ candIdx,
                                                const unsigned long long* __restrict__ candKey,
                                                const float* __restrict__ pointData,
                                                float* __restrict__ topBox,
                                                float4* __restrict__ geo,
                                                unsigned int* __restrict__ validArr) {
    int b = blockIdx.x, t = threadIdx.x;
    __shared__ unsigned long long ka[CAND];
    __shared__ unsigned int id[CAND];
    int cnt = (int)candCount[b];
    if (cnt > CAND) cnt = CAND;
    for (int x = t; x < cnt; x += 1024) {
        ka[x] = candKey[b * CAND + x];
        id[x] = candIdx[b * CAND + x];
    }
    int K0 = (cnt < PRE) ? cnt : PRE;
    // zero rows that will not be scattered
    if (t >= K0) {
        float* tb = topBox + (size_t)(b * PRE + t) * 8;
#pragma unroll
        for (int k = 0; k < 8; ++k) tb[k] = 0.f;
        geo[b * PRE + t] = make_float4(0.f, 0.f, 0.f, 0.f);
        validArr[b * PRE + t] = 0u;
    }
    __syncthreads();
    for (int x = t; x < cnt; x += 1024) {
        unsigned long long kx = ka[x];
        unsigned int ix = id[x];
        int rank = 0;
        for (int j = 0; j < cnt; ++j) {
            unsigned long long kj = ka[j];            // broadcast read
            unsigned int ij = id[j];                  // broadcast read
            rank += (int)((kj > kx) | ((kj == kx) & (ij < ix)));
        }
        if (rank < PRE) {
            const float4* pd = (const float4*)(pointData + (size_t)ix * 8);
            float4 v0 = pd[0], v1 = pd[1];
            float* tb = topBox + (size_t)(b * PRE + rank) * 8;
            tb[0] = v0.x; tb[1] = v0.y; tb[2] = v0.z; tb[3] = v0.w;
            tb[4] = v1.x; tb[5] = v1.y; tb[6] = v1.z; tb[7] = v1.w;
            geo[b * PRE + rank] = make_float4(v0.x, v0.y, v0.w, v1.x);   // x,y,l,w
            validArr[b * PRE + rank] = 1u;
        }
    }
}

// K5: overlap bit-matrix; one wave per row i, loop over upper-tri words
__global__ __launch_bounds__(256) void k5_iou(const float4* __restrict__ geo,
                                              unsigned long long* __restrict__ M) {
    int wv = threadIdx.x >> 6, lane = threadIdx.x & 63;
    int gidx = blockIdx.x * 4 + wv;        // 0..4095
    int b = gidx >> 10, i = gidx & (PRE - 1);
    float4 bi = geo[b * PRE + i];
    float x1i = bi.x - bi.z * 0.5f, x2i = bi.x + bi.z * 0.5f;
    float y1i = bi.y - bi.w * 0.5f, y2i = bi.y + bi.w * 0.5f;
    float ai = bi.z * bi.w;
    int g = i >> 6;
    unsigned long long* Mrow = M + (size_t)(b * PRE + i) * 16;
    for (int wj = g; wj < 16; ++wj) {
        int j = wj * 64 + lane;
        float4 bj = geo[b * PRE + j];
        float x1j = bj.x - bj.z * 0.5f, x2j = bj.x + bj.z * 0.5f;
        float y1j = bj.y - bj.w * 0.5f, y2j = bj.y + bj.w * 0.5f;
        float aj = bj.z * bj.w;
        float ix = fmaxf(fminf(x2i, x2j) - fmaxf(x1i, x1j), 0.0f);
        float iy = fmaxf(fminf(y2i, y2j) - fmaxf(y1i, y1j), 0.0f);
        float inter = ix * iy;
        float uni = ai + aj - inter;
        float iou = inter / fmaxf(uni, 1e-6f);
        unsigned long long m = __ballot(iou > 0.1f);
        if (lane == 0) Mrow[wj] = m;
    }
}

// K6: compact flagged rows into LDS, sparse greedy NMS, write outputs (incl. lb=0)
__global__ __launch_bounds__(256) void k6_nms(const unsigned long long* __restrict__ M,
                                              const unsigned int* __restrict__ validArr,
                                              const float* __restrict__ topBox,
                                              float* __restrict__ out0,
                                              int* __restrict__ lbOut,
                                              float* __restrict__ keepOut) {
    __shared__ unsigned long long Mc[MAXSLOT * 16];   // 48 KB
    __shared__ unsigned int slotIdx[PRE];
    __shared__ unsigned int cntSh;
    __shared__ unsigned long long suppSh[16];
    int b = blockIdx.x, tid = threadIdx.x;
    if (tid == 0) cntSh = 0;
    __syncthreads();
    for (int r = tid; r < PRE; r += 256) {
        const unsigned long long* row = M + (size_t)(b * PRE + r) * 16;
        unsigned long long w[16];
        unsigned long long o = 0ull;
#pragma unroll
        for (int l = 0; l < 16; ++l) { w[l] = row[l] & allow_mask(r, l); o |= w[l]; }
        unsigned int s = 0xFFFFFFFFu;
        if (o != 0ull) {
            unsigned int slot = atomicAdd(&cntSh, 1u);
            if (slot < MAXSLOT) {
                s = slot;
#pragma unroll
                for (int l = 0; l < 16; ++l) Mc[slot * 16 + l] = w[l];
            } else s = 0xFFFFFFFEu;
        }
        slotIdx[r] = s;
    }
    __syncthreads();
    if (tid < 64) {
        int lane = tid;
        unsigned long long supp = 0ull;                // word `lane` (lane<16)
        for (int g = 0; g < 16; ++g) {
            unsigned long long act = __ballot(slotIdx[g * 64 + lane] != 0xFFFFFFFFu);
            while (act) {
                int bit = __builtin_ctzll(act);
                act &= act - 1ull;
                int i = g * 64 + bit;
                unsigned long long wsup = __shfl(supp, g);
                bool keep_i = ((wsup >> (i & 63)) & 1ull) == 0ull;
                if (keep_i && lane < 16) {
                    unsigned int s = slotIdx[i];
                    unsigned long long add = (s < MAXSLOT)
                        ? Mc[s * 16 + lane]
                        : (M[(size_t)(b * PRE + i) * 16 + lane] & allow_mask(i, lane));
                    supp |= add;
                }
            }
        }
        if (lane < 16) suppSh[lane] = supp;
    }
    __syncthreads();
    for (int r = tid; r < PRE; r += 256) {
        bool keep = (((suppSh[r >> 6] >> (r & 63)) & 1ull) == 0ull) && (validArr[b * PRE + r] != 0u);
        float kf = keep ? 1.0f : 0.0f;
        const float* tb = topBox + (size_t)(b * PRE + r) * 8;
        float* o = out0 + (size_t)(b * PRE + r) * 8;
#pragma unroll
        for (int k = 0; k < 8; ++k) o[k] = tb[k] * kf;
        lbOut[b * PRE + r] = 0;
        keepOut[b * PRE + r] = kf;
    }
}

extern "C" void kernel_launch(void* const* d_in, const int* in_sizes, int n_in,
                              void* d_out, int out_size, void* d_ws, size_t ws_size,
                              hipStream_t stream) {
    int N = in_sizes[0] / 256;
    const float* feat = (const float*)d_in[0];
    const int* batch_idx = (const int*)d_in[1];
    const int* coor = (const int*)d_in[2];
    const float* Wcls = (const float*)d_in[3];
    const float* bcls = (const float*)d_in[4];
    const float* Wreg = (const float*)d_in[5];
    const float* breg = (const float*)d_in[6];

    char* ws = (char*)d_ws;
    size_t off = 0;
    auto take = [&](size_t bytes) -> char* {
        char* r = ws + off;
        off += (bytes + 255) & ~(size_t)255;
        return r;
    };
    float* pointData = (float*)take((size_t)N * 8 * 4);
    unsigned long long* keys = (unsigned long long*)take((size_t)N * 8);
    unsigned int* hist = (unsigned int*)take((size_t)NBATCH * NHIST * 4);
    unsigned int* Tarr = (unsigned int*)take(NBATCH * 4);
    unsigned int* candCount = (unsigned int*)take(NBATCH * 4);
    unsigned int* candIdx = (unsigned int*)take(NBATCH * CAND * 4);
    unsigned long long* candKey = (unsigned long long*)take(NBATCH * CAND * 8);
    float* topBox = (float*)take(NBATCH * PRE * 8 * 4);
    float4* geo = (float4*)take(NBATCH * PRE * 16);
    unsigned int* validArr = (unsigned int*)take(NBATCH * PRE * 4);
    unsigned long long* M = (unsigned long long*)take((size_t)NBATCH * PRE * 16 * 8);
    double* Wd3 = (double*)take(3 * 256 * 8);
    float* Wf8 = (float*)take(8 * 256 * 4);
    double* biasD = (double*)take(3 * 8);
    float* biasF = (float*)take(8 * 4);

    float* out0 = (float*)d_out;                              // (4,1024,8)
    int* lbOut = (int*)(out0 + NBATCH * PRE * 8);             // (4,1024) int32, all zero
    float* keepOut = out0 + NBATCH * PRE * 8 + NBATCH * PRE;  // (4,1024) as 0/1 float

    int pb256 = (N + 255) / 256;
    k_init<<<dim3(257), dim3(256), 0, stream>>>(Wcls, bcls, Wreg, breg, Wd3, Wf8, biasD, biasF, hist);
    k1_points<<<dim3(pb256), dim3(256), 0, stream>>>((const float4*)feat, batch_idx, coor,
                                                     Wd3, Wf8, biasD, biasF,
                                                     pointData, keys, hist, N);
    k2_thresh<<<dim3(NBATCH), dim3(256), 0, stream>>>(hist, Tarr, candCount);
    k3_compact<<<dim3(pb256), dim3(256), 0, stream>>>(batch_idx, pointData, keys, Tarr,
                                                      candCount, candIdx, candKey, N);
    k4_rank<<<dim3(NBATCH), dim3(1024), 0, stream>>>(candCount, candIdx, candKey,
                                                     pointData, topBox, geo, validArr);
    k5_iou<<<dim3(NBATCH * PRE / 4), dim3(256), 0, stream>>>(geo, M);
    k6_nms<<<dim3(NBATCH), dim3(256), 0, stream>>>(M, validArr, topBox, out0, lbOut, keepOut);
}